// Round 14
// baseline (41.789 us; speedup 1.0000x reference)
//
#include <hip/hip_runtime.h>

// NCuts loss: seg [8,4,224,224], padded_seg [8,4,232,232],
// weight [8,1,224,224,9,9], sum_weight [8,1,224,224] -> out[8] (fp32)
//
// R13 structure verbatim (1024 blocks = 8img x 32rowgrp x 4strip, 7x56 px,
// 512 thr, 3 blocks/CU, weight dbuf global_load_lds prefetch, simple
// __syncthreads loop, XCD swizzle) with ONE change:
//   psg window stored as TWO class-pair float2 arrays
//     psgA[15][64] = {c0,c1},  psgB[15][64] = {c2,c3}
//   -> tap = 1 ds_read_b32 (weight) + 2 ds_read_b64 (all 4 classes),
//   was 1 + 4 ds_read_b32. Cuts the dominant LDS-instruction cost ~30%.
//   (b64 lane-stride 8B = standard coalesced pattern; R7's failed variant
//   was 16B-stride b128.) psg staged once via register pair-packing
//   (coalesced scalar loads, prologue-only, loop-local temps).

constexpr int NN  = 8;
constexpr int KK  = 4;
constexpr int HH  = 224;
constexpr int WW  = 224;
constexpr int PAD = 4;                   // RADIUS-1
constexpr int HP  = HH + 2 * PAD;        // 232
constexpr int WP  = WW + 2 * PAD;        // 232
constexpr int NWIN = 81;
constexpr int PIX = HH * WW;             // 50176
constexpr int TPB = 512;                 // 8 waves
constexpr int PPB = 56;                  // strip width
constexpr int RPB = 7;                   // rows per block
constexpr int CSP = WW / PPB;            // 4 col-strips
constexpr int GPI = HH / RPB;            // 32 row-groups
constexpr int BPI = GPI * CSP;           // 128 blocks per image
constexpr int NBLK = NN * BPI;           // 1024 blocks
constexpr int PLANE = HP * WP;           // 53824
constexpr int WCOL = PPB + 8;            // 64 window cols
constexpr int NSLOT = RPB + 8;           // 15 window rows
constexpr int PSG_SITES = NSLOT * WCOL;  // 960 (slot,col) sites
constexpr int WSLAB = PPB * NWIN;        // 4536 floats per weight tile
constexpr int WF4 = WSLAB / 4;           // 1134 f4

#define GLL16(gptr, lptr)                                            \
    __builtin_amdgcn_global_load_lds(                                \
        (const __attribute__((address_space(1))) void*)(gptr),       \
        (__attribute__((address_space(3))) void*)(lptr), 16, 0, 0)

template<int T0, int T1>
__device__ inline void do_taps(const float* __restrict__ lwp,
                               const float2* __restrict__ pA,
                               const float2* __restrict__ pB,
                               float acc[KK], float& wsum) {
#pragma unroll
    for (int t = T0; t < T1; ++t) {
        const int m = t / 9;
        const int j = t - 9 * m;              // compile-time after unroll
        const float wv = lwp[t];              // ds_read_b32
        wsum += wv;
        const float2 x = pA[m * WCOL + j];    // ds_read_b64 {c0,c1}
        const float2 y = pB[m * WCOL + j];    // ds_read_b64 {c2,c3}
        acc[0] += x.x * wv;
        acc[1] += x.y * wv;
        acc[2] += y.x * wv;
        acc[3] += y.y * wv;
    }
}

__global__ __launch_bounds__(TPB, 6) void ncuts_stage1(
    const float* __restrict__ seg, const float* __restrict__ pseg,
    const float* __restrict__ wgt, const float* __restrict__ swgt,
    float* __restrict__ part)
{
    const int hw   = blockIdx.x;
    const int b    = (hw & 7) * (NBLK / 8) + (hw >> 3);  // XCD swizzle (bijective)
    const int n    = b / BPI;
    const int r    = b - n * BPI;
    const int rg   = r >> 2;                 // row-group 0..31
    const int cs   = r & 3;                  // col-strip 0..3
    const int h0   = rg * RPB;
    const int w0   = cs * PPB;
    const int tid  = threadIdx.x;
    const int wv_  = tid >> 6;               // 0..7
    const int lane = tid & 63;

    __shared__ float  lds_w[2 * WSLAB];      // 36288 B
    __shared__ float2 psgA[PSG_SITES];       // 7680 B {c0,c1}
    __shared__ float2 psgB[PSG_SITES];       // 7680 B {c2,c3}
    __shared__ float  lred[8][8];            // 256 B -> 51904 B total

    const size_t nb = (size_t)n * KK * PLANE;

    // ---- weight tile stager (R13-proven) ----
    auto stage_w = [&](int buf, int s) {
        const float4* wsrc = (const float4*)(
            wgt + ((size_t)n * PIX + (size_t)(h0 + s) * WW + w0) * NWIN);
        float* base = lds_w + buf * WSLAB;
#pragma unroll
        for (int k = 0; k < 3; ++k) {
            const int i = k * TPB + tid;
            if (i < WF4)
                GLL16(wsrc + i, base + ((k * TPB + (tid & ~63)) << 2));
        }
    };

    stage_w(0, 0);                            // async: weight tile 0

    // ---- psg window prologue: register pair-packing, coalesced loads ----
    for (int i = tid; i < PSG_SITES; i += TPB) {
        const int slot = i >> 6;              // /WCOL
        const int col  = i & 63;
        const float* g = pseg + nb + (size_t)(h0 + slot) * WP + (w0 + col);
        const float a0 = g[0];
        const float a1 = g[PLANE];
        const float a2 = g[2 * (size_t)PLANE];
        const float a3 = g[3 * (size_t)PLANE];
        psgA[i] = make_float2(a0, a1);
        psgB[i] = make_float2(a2, a3);
    }

    float rA[KK] = {0.f, 0.f, 0.f, 0.f};
    float rV[KK] = {0.f, 0.f, 0.f, 0.f};

    __syncthreads();   // psg window + weight tile 0 landed

    int cur = 0;
#pragma unroll 1
    for (int s = 0; s < RPB; ++s) {
        // ---- prefetch next row-tile's weights into the other buffer ----
        if (s + 1 < RPB) stage_w(cur ^ 1, s + 1);

        // ---- compute row s from LDS; fold into rA/rV ----
        if (lane < PPB) {
            const float2* pA = psgA + (size_t)s * WCOL + lane;
            const float2* pB = psgB + (size_t)s * WCOL + lane;
            float segv[KK];
            {   // seg = window interior: slot s+4, window col lane+4
                const float2 sx = pA[4 * WCOL + 4];
                const float2 sy = pB[4 * WCOL + 4];
                segv[0] = sx.x; segv[1] = sx.y;
                segv[2] = sy.x; segv[3] = sy.y;
            }
            const float* lwp = lds_w + cur * WSLAB + lane * NWIN;
            float acc[KK] = {0.f, 0.f, 0.f, 0.f};
            float wsum = 0.f;
            switch (wv_) {
                case 0:  do_taps<0, 10>(lwp, pA, pB, acc, wsum); break;
                case 1:  do_taps<10, 20>(lwp, pA, pB, acc, wsum); break;
                case 2:  do_taps<20, 30>(lwp, pA, pB, acc, wsum); break;
                case 3:  do_taps<30, 40>(lwp, pA, pB, acc, wsum); break;
                case 4:  do_taps<40, 50>(lwp, pA, pB, acc, wsum); break;
                case 5:  do_taps<50, 60>(lwp, pA, pB, acc, wsum); break;
                case 6:  do_taps<60, 70>(lwp, pA, pB, acc, wsum); break;
                default: do_taps<70, 81>(lwp, pA, pB, acc, wsum); break;
            }
#pragma unroll
            for (int c = 0; c < KK; ++c) {
                rA[c] += acc[c] * segv[c];
                rV[c] += wsum   * segv[c];
            }
        }
        __syncthreads();   // tile consumed; prefetch drained (overlap across
        cur ^= 1;          //   the 3 resident blocks on this CU)
    }

    // ---- single block-end reduction ----
    float vals[8] = { rA[0], rA[1], rA[2], rA[3], rV[0], rV[1], rV[2], rV[3] };
#pragma unroll
    for (int i = 0; i < 8; ++i) {
        float v = vals[i];
#pragma unroll
        for (int off = 32; off > 0; off >>= 1) v += __shfl_down(v, off, 64);
        if (lane == 0) lred[wv_][i] = v;
    }
    __syncthreads();
    if (tid < 8) {
        float ssum = 0.f;
#pragma unroll
        for (int w = 0; w < 8; ++w) ssum += lred[w][tid];
        part[(size_t)b * 8 + tid] = ssum;
    }
}

__global__ __launch_bounds__(256) void ncuts_stage2(
    const float* __restrict__ part, float* __restrict__ out)
{
    const int n   = blockIdx.x;
    const int tid = threadIdx.x;

    float vals[8] = {0.f, 0.f, 0.f, 0.f, 0.f, 0.f, 0.f, 0.f};
    for (int bb = tid; bb < BPI; bb += 256) {       // 128 entries per image
        const float* q = part + ((size_t)(n * BPI + bb)) * 8;
#pragma unroll
        for (int i = 0; i < 8; ++i) vals[i] += q[i];
    }

    __shared__ float lred[4][8];
    const int lane = tid & 63;
    const int wv_  = tid >> 6;
#pragma unroll
    for (int i = 0; i < 8; ++i) {
        float v = vals[i];
#pragma unroll
        for (int off = 32; off > 0; off >>= 1) v += __shfl_down(v, off, 64);
        if (lane == 0) lred[wv_][i] = v;
    }
    __syncthreads();
    if (tid == 0) {
        float assoc = 0.f;
#pragma unroll
        for (int k = 0; k < 4; ++k) {
            const float A = lred[0][k] + lred[1][k] + lred[2][k] + lred[3][k];
            const float V = lred[0][4 + k] + lred[1][4 + k] + lred[2][4 + k] + lred[3][4 + k];
            assoc += A / V;
        }
        out[n] = 4.0f - assoc;
    }
}

extern "C" void kernel_launch(void* const* d_in, const int* in_sizes, int n_in,
                              void* d_out, int out_size, void* d_ws, size_t ws_size,
                              hipStream_t stream) {
    const float* seg  = (const float*)d_in[0];
    const float* pseg = (const float*)d_in[1];
    const float* wgt  = (const float*)d_in[2];
    const float* swgt = (const float*)d_in[3];
    float* out  = (float*)d_out;
    float* part = (float*)d_ws;   // 1024 blocks * 8 floats = 32768 B

    ncuts_stage1<<<NBLK, TPB, 0, stream>>>(seg, pseg, wgt, swgt, part);
    ncuts_stage2<<<NN, 256, 0, stream>>>(part, out);
}

// Round 15
// 35.097 us; speedup vs baseline: 1.1907x; 1.1907x over previous
//
#include <hip/hip_runtime.h>

// NCuts loss: seg [8,4,224,224], padded_seg [8,4,232,232],
// weight [8,1,224,224,9,9], sum_weight [8,1,224,224] -> out[8] (fp32)
//
// R13 structure (1024 blocks = 8img x 32rowgrp x 4strip, 7rows x 56cols,
// 512 thr = 8 waves, 3 blocks/CU, psg [15][4][64] via global_load_lds,
// weight dbuf global_load_lds prefetch, simple __syncthreads loop, XCD
// swizzle) with the tap loop rebuilt on DPP lane-shifts:
//   - a wave's 64 lanes = the 64 window cols, so ONE ds_read_b32 per
//     (m-row, class) fetches the whole row; psg[lane+j] for tap j comes
//     from a cumulative wave_shl:1 DPP mov (VALU pipe, not LDS pipe).
//   - psg LDS reads: 36 -> 4 per m-row per wave (9x fewer). Weight reads
//     unchanged (lane-private, ds_read2-mergeable).
//   - work split: wave w owns m-row w (w=0..7); row 8's classes 0..3 on
//     waves 0..3 (wave 0 also owns row-8 wsum). Compute unguarded (DPP
//     needs all 64 lanes); fold guarded by lane<PPB as before.

constexpr int NN  = 8;
constexpr int KK  = 4;
constexpr int HH  = 224;
constexpr int WW  = 224;
constexpr int PAD = 4;                   // RADIUS-1
constexpr int HP  = HH + 2 * PAD;        // 232
constexpr int WP  = WW + 2 * PAD;        // 232
constexpr int NWIN = 81;
constexpr int PIX = HH * WW;             // 50176
constexpr int TPB = 512;                 // 8 waves
constexpr int PPB = 56;                  // strip width
constexpr int RPB = 7;                   // rows per block
constexpr int CSP = WW / PPB;            // 4 col-strips
constexpr int GPI = HH / RPB;            // 32 row-groups
constexpr int BPI = GPI * CSP;           // 128 blocks per image
constexpr int NBLK = NN * BPI;           // 1024 blocks
constexpr int PLANE = HP * WP;           // 53824
constexpr int WCOL = PPB + 8;            // 64 window cols
constexpr int NSLOT = RPB + 8;           // 15 window rows
constexpr int PSG_F4 = NSLOT * KK * (WCOL / 4);  // 960 f4 = 15.4 KB
constexpr int WSLAB = PPB * NWIN;        // 4536 floats per weight tile
constexpr int WF4 = WSLAB / 4;           // 1134 f4

#define GLL16(gptr, lptr)                                            \
    __builtin_amdgcn_global_load_lds(                                \
        (const __attribute__((address_space(1))) void*)(gptr),       \
        (__attribute__((address_space(3))) void*)(lptr), 16, 0, 0)

// lane i <- lane i+1 (zero-fill at lane 63). wave_shl per LLVM DppCtrl=0x130;
// direction per rocPRIM convention: row_shr pulls from lower lanes, so
// wave_shl pulls from higher.
__device__ __forceinline__ float dpp_shl1(float x) {
    int r = __builtin_amdgcn_update_dpp(
        0, __builtin_bit_cast(int, x), 0x130 /*WAVE_SHL1*/, 0xF, 0xF, true);
    return __builtin_bit_cast(float, r);
}

// full window-row M, all 4 classes, via DPP shifts
template<int M>
__device__ __forceinline__ void do_mrow(const float* __restrict__ lwp,
                                        const float* __restrict__ pbase,
                                        float acc[KK], float& wsum) {
    float wv[9];
#pragma unroll
    for (int j = 0; j < 9; ++j) wv[j] = lwp[9 * M + j];
#pragma unroll
    for (int j = 0; j < 9; ++j) wsum += wv[j];
    float q0 = pbase[(M * KK + 0) * WCOL];
    float q1 = pbase[(M * KK + 1) * WCOL];
    float q2 = pbase[(M * KK + 2) * WCOL];
    float q3 = pbase[(M * KK + 3) * WCOL];
    acc[0] += q0 * wv[0]; acc[1] += q1 * wv[0];
    acc[2] += q2 * wv[0]; acc[3] += q3 * wv[0];
#pragma unroll
    for (int j = 1; j < 9; ++j) {
        q0 = dpp_shl1(q0); q1 = dpp_shl1(q1);
        q2 = dpp_shl1(q2); q3 = dpp_shl1(q3);
        acc[0] += q0 * wv[j]; acc[1] += q1 * wv[j];
        acc[2] += q2 * wv[j]; acc[3] += q3 * wv[j];
    }
}

// single class C of window-row 8 (optionally owns row-8 wsum)
template<int C, bool WSUM8>
__device__ __forceinline__ void do_m8c(const float* __restrict__ lwp,
                                       const float* __restrict__ pbase,
                                       float acc[KK], float& wsum) {
    float wv[9];
#pragma unroll
    for (int j = 0; j < 9; ++j) wv[j] = lwp[72 + j];
    if (WSUM8) {
#pragma unroll
        for (int j = 0; j < 9; ++j) wsum += wv[j];
    }
    float q = pbase[(8 * KK + C) * WCOL];
    acc[C] += q * wv[0];
#pragma unroll
    for (int j = 1; j < 9; ++j) {
        q = dpp_shl1(q);
        acc[C] += q * wv[j];
    }
}

__global__ __launch_bounds__(TPB, 6) void ncuts_stage1(
    const float* __restrict__ seg, const float* __restrict__ pseg,
    const float* __restrict__ wgt, const float* __restrict__ swgt,
    float* __restrict__ part)
{
    const int hw   = blockIdx.x;
    const int b    = (hw & 7) * (NBLK / 8) + (hw >> 3);  // XCD swizzle (bijective)
    const int n    = b / BPI;
    const int r    = b - n * BPI;
    const int rg   = r >> 2;                 // row-group 0..31
    const int cs   = r & 3;                  // col-strip 0..3
    const int h0   = rg * RPB;
    const int w0   = cs * PPB;
    const int tid  = threadIdx.x;
    const int wv_  = tid >> 6;               // 0..7
    const int lane = tid & 63;

    __shared__ float lds_w[2 * WSLAB];                 // 36288 B
    __shared__ float psg_lds[NSLOT * KK * WCOL];       // 15360 B
    __shared__ float lred[8][8];                       // 256 B -> 51904 B

    const size_t nb = (size_t)n * KK * PLANE;

    // ---- weight tile stager (R13-proven) ----
    auto stage_w = [&](int buf, int s) {
        const float4* wsrc = (const float4*)(
            wgt + ((size_t)n * PIX + (size_t)(h0 + s) * WW + w0) * NWIN);
        float* base = lds_w + buf * WSLAB;
#pragma unroll
        for (int k = 0; k < 3; ++k) {
            const int i = k * TPB + tid;
            if (i < WF4)
                GLL16(wsrc + i, base + ((k * TPB + (tid & ~63)) << 2));
        }
    };

    stage_w(0, 0);                            // async: weight tile 0

    // ---- psg window prologue: [15 slots][4 cls][64 cols], 960 f4 ----
#pragma unroll
    for (int k = 0; k < 2; ++k) {
        const int i = k * TPB + tid;
        if (i < PSG_F4) {
            const int slot = i >> 6;              // 64 f4 per slot
            const int c    = (i >> 4) & 3;
            const int c4   = i & 15;
            const float* src = pseg + nb + (size_t)c * PLANE +
                               (size_t)(h0 + slot) * WP + w0 + c4 * 4;
            GLL16(src, psg_lds + ((k * TPB + (tid & ~63)) << 2));
        }
    }

    float rA[KK] = {0.f, 0.f, 0.f, 0.f};
    float rV[KK] = {0.f, 0.f, 0.f, 0.f};

    __syncthreads();   // psg window + weight tile 0 landed

    const int wlane = (lane < PPB) ? lane : (PPB - 1);   // clamp for w-reads

    int cur = 0;
#pragma unroll 1
    for (int s = 0; s < RPB; ++s) {
        // ---- prefetch next row-tile's weights into the other buffer ----
        if (s + 1 < RPB) stage_w(cur ^ 1, s + 1);

        // ---- compute row s: ALL 64 lanes (DPP needs full exec) ----
        {
            const float* lwp   = lds_w + cur * WSLAB + wlane * NWIN;
            const float* pbase = psg_lds + (size_t)s * KK * WCOL + lane;
            float acc[KK] = {0.f, 0.f, 0.f, 0.f};
            float wsum = 0.f;
            switch (wv_) {
                case 0: do_mrow<0>(lwp, pbase, acc, wsum);
                        do_m8c<0, true>(lwp, pbase, acc, wsum);  break;
                case 1: do_mrow<1>(lwp, pbase, acc, wsum);
                        do_m8c<1, false>(lwp, pbase, acc, wsum); break;
                case 2: do_mrow<2>(lwp, pbase, acc, wsum);
                        do_m8c<2, false>(lwp, pbase, acc, wsum); break;
                case 3: do_mrow<3>(lwp, pbase, acc, wsum);
                        do_m8c<3, false>(lwp, pbase, acc, wsum); break;
                case 4: do_mrow<4>(lwp, pbase, acc, wsum); break;
                case 5: do_mrow<5>(lwp, pbase, acc, wsum); break;
                case 6: do_mrow<6>(lwp, pbase, acc, wsum); break;
                default: do_mrow<7>(lwp, pbase, acc, wsum); break;
            }
            if (lane < PPB) {
                float segv[KK];
#pragma unroll
                for (int c = 0; c < KK; ++c)      // seg = window interior
                    segv[c] = pbase[((4 * KK) + c) * WCOL + 4];
#pragma unroll
                for (int c = 0; c < KK; ++c) {
                    rA[c] += acc[c] * segv[c];
                    rV[c] += wsum   * segv[c];
                }
            }
        }
        __syncthreads();   // tile consumed; prefetch drained (overlap across
        cur ^= 1;          //   the 3 resident blocks on this CU)
    }

    // ---- single block-end reduction ----
    float vals[8] = { rA[0], rA[1], rA[2], rA[3], rV[0], rV[1], rV[2], rV[3] };
#pragma unroll
    for (int i = 0; i < 8; ++i) {
        float v = vals[i];
#pragma unroll
        for (int off = 32; off > 0; off >>= 1) v += __shfl_down(v, off, 64);
        if (lane == 0) lred[wv_][i] = v;
    }
    __syncthreads();
    if (tid < 8) {
        float ssum = 0.f;
#pragma unroll
        for (int w = 0; w < 8; ++w) ssum += lred[w][tid];
        part[(size_t)b * 8 + tid] = ssum;
    }
}

__global__ __launch_bounds__(256) void ncuts_stage2(
    const float* __restrict__ part, float* __restrict__ out)
{
    const int n   = blockIdx.x;
    const int tid = threadIdx.x;

    float vals[8] = {0.f, 0.f, 0.f, 0.f, 0.f, 0.f, 0.f, 0.f};
    for (int bb = tid; bb < BPI; bb += 256) {       // 128 entries per image
        const float* q = part + ((size_t)(n * BPI + bb)) * 8;
#pragma unroll
        for (int i = 0; i < 8; ++i) vals[i] += q[i];
    }

    __shared__ float lred[4][8];
    const int lane = tid & 63;
    const int wv_  = tid >> 6;
#pragma unroll
    for (int i = 0; i < 8; ++i) {
        float v = vals[i];
#pragma unroll
        for (int off = 32; off > 0; off >>= 1) v += __shfl_down(v, off, 64);
        if (lane == 0) lred[wv_][i] = v;
    }
    __syncthreads();
    if (tid == 0) {
        float assoc = 0.f;
#pragma unroll
        for (int k = 0; k < 4; ++k) {
            const float A = lred[0][k] + lred[1][k] + lred[2][k] + lred[3][k];
            const float V = lred[0][4 + k] + lred[1][4 + k] + lred[2][4 + k] + lred[3][4 + k];
            assoc += A / V;
        }
        out[n] = 4.0f - assoc;
    }
}

extern "C" void kernel_launch(void* const* d_in, const int* in_sizes, int n_in,
                              void* d_out, int out_size, void* d_ws, size_t ws_size,
                              hipStream_t stream) {
    const float* seg  = (const float*)d_in[0];
    const float* pseg = (const float*)d_in[1];
    const float* wgt  = (const float*)d_in[2];
    const float* swgt = (const float*)d_in[3];
    float* out  = (float*)d_out;
    float* part = (float*)d_ws;   // 1024 blocks * 8 floats = 32768 B

    ncuts_stage1<<<NBLK, TPB, 0, stream>>>(seg, pseg, wgt, swgt, part);
    ncuts_stage2<<<NN, 256, 0, stream>>>(part, out);
}